// Round 11
// baseline (479.016 us; speedup 1.0000x reference)
//
#include <hip/hip_runtime.h>
#include <hip/hip_bf16.h>

#define B_   4
#define DENC 512
#define T_   200
#define DDEC 640
#define U_   100
#define H_   640
#define V_   1025
#define VPAD 1152

typedef float f32x4 __attribute__((ext_vector_type(4)));
typedef __bf16 bf16x8 __attribute__((ext_vector_type(8)));
typedef unsigned short u16x8 __attribute__((ext_vector_type(8)));

__device__ __forceinline__ float bf2f(unsigned short s) {
    return __uint_as_float(((unsigned)s) << 16);
}

// relu(a), relu(b) packed to 2x bf16 in one dword
__device__ __forceinline__ unsigned pkrelu(float a, float b) {
    float lo = fmaxf(a, 0.f);
    float hi = fmaxf(b, 0.f);
    unsigned r;
    asm("v_cvt_pk_bf16_f32 %0, %1, %2" : "=v"(r) : "v"(lo), "v"(hi));
    return r;
}

__device__ __forceinline__ void gload_lds16(const void* g, void* l) {
    __builtin_amdgcn_global_load_lds(
        (const __attribute__((address_space(1))) unsigned int*)g,
        (__attribute__((address_space(3))) unsigned int*)l, 16, 0, 0);
}

// ---------------- K1: enc_proj[b,t,h] = f32( sum_d enc[b,d,t]*W_enc[d,h] + b_enc[h] )
// (round-8 proven structure; output stays f32 now)
__global__ __launch_bounds__(128) void enc_proj_kernel(
    const float* __restrict__ enc, const float* __restrict__ W,
    const float* __restrict__ bias, float* __restrict__ out)
{
    int hc = blockIdx.x, tg = blockIdx.y, b = blockIdx.z;
    int h  = hc * 128 + threadIdx.x;
    int t0 = tg * 8;
    const float* ec = enc + (size_t)b * DENC * T_ + t0;
    const float* Wc = W + h;
    float acc[8] = {0.f,0.f,0.f,0.f,0.f,0.f,0.f,0.f};
    #pragma unroll 8
    for (int d = 0; d < DENC; ++d) {
        float w = Wc[(size_t)d * H_];
        float4 e0 = *(const float4*)(ec + (size_t)d * T_);
        float4 e1 = *(const float4*)(ec + (size_t)d * T_ + 4);
        acc[0] += w * e0.x; acc[1] += w * e0.y; acc[2] += w * e0.z; acc[3] += w * e0.w;
        acc[4] += w * e1.x; acc[5] += w * e1.y; acc[6] += w * e1.z; acc[7] += w * e1.w;
    }
    float bb = bias[h];
    #pragma unroll
    for (int i = 0; i < 8; ++i)
        out[((size_t)b * T_ + t0 + i) * H_ + h] = acc[i] + bb;
}

// ---------------- K2: dec_proj (round-8 structure, f32 out)
__global__ __launch_bounds__(128) void dec_proj_kernel(
    const float* __restrict__ dec, const float* __restrict__ W,
    const float* __restrict__ bias, float* __restrict__ out)
{
    int hc = blockIdx.x, ug = blockIdx.y, b = blockIdx.z;
    int h  = hc * 128 + threadIdx.x;
    int u0 = ug * 4;
    const float* dc = dec + (size_t)b * DDEC * U_ + u0;
    const float* Wc = W + h;
    float acc[4] = {0.f,0.f,0.f,0.f};
    #pragma unroll 8
    for (int d = 0; d < DDEC; ++d) {
        float w = Wc[(size_t)d * H_];
        float4 e0 = *(const float4*)(dc + (size_t)d * U_);
        acc[0] += w * e0.x; acc[1] += w * e0.y; acc[2] += w * e0.z; acc[3] += w * e0.w;
    }
    float bb = bias[h];
    #pragma unroll
    for (int i = 0; i < 4; ++i)
        out[((size_t)b * U_ + u0 + i) * H_ + h] = acc[i] + bb;
}

// ---------------- K3: Wt[v][h] = bf16(W_out[h][v]) (v padded to VPAD with zeros)
__global__ __launch_bounds__(256) void wt_transpose_kernel(
    const float* __restrict__ W, unsigned short* __restrict__ Wt)
{
    int hc = blockIdx.x, vc = blockIdx.y;
    int h0 = hc * 64, v0 = vc * 64;
    __shared__ float tile[64][65];
    int tid = threadIdx.x;
    #pragma unroll
    for (int it = 0; it < 16; ++it) {
        int hl = it * 4 + (tid >> 6);
        int vl = tid & 63;
        int v = v0 + vl;
        tile[hl][vl] = (v < V_) ? W[(size_t)(h0 + hl) * V_ + v] : 0.f;
    }
    __syncthreads();
    #pragma unroll
    for (int it = 0; it < 16; ++it) {
        int vl = it * 4 + (tid >> 6);
        int hl = tid & 63;
        __bf16 bv = (__bf16)tile[hl][vl];
        Wt[(size_t)(v0 + vl) * H_ + h0 + hl] = *(unsigned short*)&bv;
    }
}

// ---------------- K4: round-8 joint skeleton (proven 287us), f32-source A-build
// 256 thr = 4 waves (1x4), wave = 64 rows x 64 cols, acc[4][4], BK=32, 20 K-steps.
// A built in-LDS from f32 encP+decP (add+max+cvt_pk), B staged via global_load_lds.
// Both LDS tiles double-buffered; chunk-XOR swizzle phys = kc ^ ((row>>1)&3).
__global__ __launch_bounds__(256) void joint_kernel(
    const float* __restrict__ encP,            // [B,T,H] f32
    const float* __restrict__ decP,            // [B,U,H] f32
    const unsigned short* __restrict__ Wt,     // [VPAD][H] bf16
    const float* __restrict__ b_out,           // [V]
    float* __restrict__ out)                   // [B,T,U,V] f32
{
    __shared__ uint4 LA[2][64][4];             // 8 KB
    __shared__ uint4 LB[2][256][4];            // 32 KB

    int vi = blockIdx.x;                       // 0..3
    int tu = blockIdx.y;                       // 0..324
    int b  = blockIdx.z;
    int tt = tu / 13, ut = tu % 13;
    int t0 = tt * 8, u0 = ut * 8, vb = vi * 256;
    int tid = threadIdx.x;
    int lane = tid & 63, w = tid >> 6;         // w = wave = col-group 0..3
    int lrow = lane & 15, kg = lane >> 4;

    // ---- A-build mapping: thread owns row r (0..63), chunk kc (0..3) = 8 k-elems
    int r  = tid >> 2, kc = tid & 3;
    int ta = t0 + (r >> 3);                    // always < 200 (t exact)
    int ua = u0 + (r & 7); if (ua > U_ - 1) ua = U_ - 1;
    const float* eR = encP + ((size_t)b * T_ + ta) * H_ + kc * 8;
    const float* dR = decP + ((size_t)b * U_ + ua) * H_ + kc * 8;
    int fA = (r >> 1) & 3;

    // ---- B gload mapping: wave w stages local cols 64w..64w+63; 4 instrs of 16 cols
    int pcB = lane & 3;
    const unsigned short* gB[4];
    #pragma unroll
    for (int m = 0; m < 4; ++m) {
        int cl = w * 64 + m * 16 + (lane >> 2);
        gB[m] = Wt + (size_t)(vb + cl) * H_ + (pcB ^ ((cl >> 1) & 3)) * 8;
    }

    f32x4 acc[4][4];
    #pragma unroll
    for (int i = 0; i < 4; ++i)
        #pragma unroll
        for (int j = 0; j < 4; ++j)
            acc[i][j] = (f32x4){0.f, 0.f, 0.f, 0.f};

    // ---- prologue: stage k-step 0 into buf 0
    {
        float4 E0 = *(const float4*)(eR);
        float4 E1 = *(const float4*)(eR + 4);
        float4 D0 = *(const float4*)(dR);
        float4 D1 = *(const float4*)(dR + 4);
        uint4 x;
        x.x = pkrelu(E0.x + D0.x, E0.y + D0.y);
        x.y = pkrelu(E0.z + D0.z, E0.w + D0.w);
        x.z = pkrelu(E1.x + D1.x, E1.y + D1.y);
        x.w = pkrelu(E1.z + D1.z, E1.w + D1.w);
        LA[0][r][kc ^ fA] = x;
        #pragma unroll
        for (int m = 0; m < 4; ++m)
            gload_lds16(gB[m], &LB[0][w * 64 + m * 16][0]);
    }
    __syncthreads();

    // ---- main K loop: 20 steps of K=32
    #pragma unroll 2
    for (int kt = 0; kt < 20; ++kt) {
        int cur = kt & 1;
        float4 E0n, E1n, D0n, D1n;
        if (kt < 19) {
            const float* e2 = eR + (kt + 1) * 32;
            const float* d2 = dR + (kt + 1) * 32;
            E0n = *(const float4*)(e2); E1n = *(const float4*)(e2 + 4);
            D0n = *(const float4*)(d2); D1n = *(const float4*)(d2 + 4);
            #pragma unroll
            for (int m = 0; m < 4; ++m)
                gload_lds16(gB[m] + (kt + 1) * 32, &LB[cur ^ 1][w * 64 + m * 16][0]);
        }
        bf16x8 a[4], bq[4];
        #pragma unroll
        for (int i = 0; i < 4; ++i) {
            int row = i * 16 + lrow;
            a[i] = __builtin_bit_cast(bf16x8, LA[cur][row][kg ^ ((row >> 1) & 3)]);
        }
        #pragma unroll
        for (int j = 0; j < 4; ++j) {
            int col = w * 64 + j * 16 + lrow;
            bq[j] = __builtin_bit_cast(bf16x8, LB[cur][col][kg ^ ((col >> 1) & 3)]);
        }
        #pragma unroll
        for (int i = 0; i < 4; ++i)
            #pragma unroll
            for (int j = 0; j < 4; ++j)
                acc[i][j] = __builtin_amdgcn_mfma_f32_16x16x32_bf16(a[i], bq[j], acc[i][j], 0, 0, 0);
        if (kt < 19) {
            uint4 x;
            x.x = pkrelu(E0n.x + D0n.x, E0n.y + D0n.y);
            x.y = pkrelu(E0n.z + D0n.z, E0n.w + D0n.w);
            x.z = pkrelu(E1n.x + D1n.x, E1n.y + D1n.y);
            x.w = pkrelu(E1n.z + D1n.z, E1n.w + D1n.w);
            LA[cur ^ 1][r][kc ^ fA] = x;
        }
        __syncthreads();
    }

    // ---- epilogue: D col = lane&15, row = kg*4 + q   (v < 1024 always)
    #pragma unroll
    for (int j = 0; j < 4; ++j) {
        int v = vb + w * 64 + j * 16 + lrow;
        float bo = b_out[v];
        #pragma unroll
        for (int i = 0; i < 4; ++i) {
            #pragma unroll
            for (int q = 0; q < 4; ++q) {
                int row = i * 16 + kg * 4 + q;
                int t = t0 + (row >> 3);
                int u = u0 + (row & 7);
                if (u < U_)
                    out[(((size_t)b * T_ + t) * U_ + u) * V_ + v] = acc[i][j][q] + bo;
            }
        }
    }
}

// ---------------- K5: last output column v=1024 (f32 enc/dec reads)
__global__ __launch_bounds__(256) void lastcol_kernel(
    const float* __restrict__ encP, const float* __restrict__ decP,
    const unsigned short* __restrict__ Wt, const float* __restrict__ b_out,
    float* __restrict__ out)
{
    int idx = blockIdx.x * 256 + threadIdx.x;
    if (idx >= B_ * T_ * U_) return;
    int u = idx % U_;
    int t = (idx / U_) % T_;
    int b = idx / (U_ * T_);
    const float4* e = (const float4*)(encP + ((size_t)b * T_ + t) * H_);
    const float4* d = (const float4*)(decP + ((size_t)b * U_ + u) * H_);
    const u16x8* wv = (const u16x8*)(Wt + (size_t)1024 * H_);
    float acc = 0.f;
    for (int c = 0; c < H_ / 8; ++c) {
        float4 e0 = e[2*c], e1 = e[2*c+1];
        float4 d0 = d[2*c], d1 = d[2*c+1];
        u16x8 wq = wv[c];
        acc += fmaxf(e0.x + d0.x, 0.f) * bf2f(wq[0]);
        acc += fmaxf(e0.y + d0.y, 0.f) * bf2f(wq[1]);
        acc += fmaxf(e0.z + d0.z, 0.f) * bf2f(wq[2]);
        acc += fmaxf(e0.w + d0.w, 0.f) * bf2f(wq[3]);
        acc += fmaxf(e1.x + d1.x, 0.f) * bf2f(wq[4]);
        acc += fmaxf(e1.y + d1.y, 0.f) * bf2f(wq[5]);
        acc += fmaxf(e1.z + d1.z, 0.f) * bf2f(wq[6]);
        acc += fmaxf(e1.w + d1.w, 0.f) * bf2f(wq[7]);
    }
    out[((size_t)(b * T_ + t) * U_ + u) * V_ + 1024] = acc + b_out[1024];
}

extern "C" void kernel_launch(void* const* d_in, const int* in_sizes, int n_in,
                              void* d_out, int out_size, void* d_ws, size_t ws_size,
                              hipStream_t stream) {
    const float* enc    = (const float*)d_in[0];
    const float* dec    = (const float*)d_in[1];
    const float* W_enc  = (const float*)d_in[2];
    const float* b_enc  = (const float*)d_in[3];
    const float* W_pred = (const float*)d_in[4];
    const float* b_pred = (const float*)d_in[5];
    const float* W_out  = (const float*)d_in[6];
    const float* b_out  = (const float*)d_in[7];
    float* out = (float*)d_out;

    char* ws = (char*)d_ws;
    float* encP = (float*)ws;                               // 4*200*640*4 = 2,048,000 B
    float* decP = (float*)(ws + 2048000);                   // 4*100*640*4 = 1,024,000 B
    unsigned short* Wt = (unsigned short*)(ws + 3072000);   // 1152*640*2  = 1,474,560 B

    enc_proj_kernel<<<dim3(5, 25, 4), 128, 0, stream>>>(enc, W_enc, b_enc, encP);
    dec_proj_kernel<<<dim3(5, 25, 4), 128, 0, stream>>>(dec, W_pred, b_pred, decP);
    wt_transpose_kernel<<<dim3(10, 18), 256, 0, stream>>>(W_out, Wt);
    joint_kernel<<<dim3(4, 325, 4), 256, 0, stream>>>(encP, decP, Wt, b_out, out);
    lastcol_kernel<<<dim3((B_ * T_ * U_ + 255) / 256), 256, 0, stream>>>(
        encP, decP, Wt, b_out, out);
}

// Round 12
// 448.534 us; speedup vs baseline: 1.0680x; 1.0680x over previous
//
#include <hip/hip_runtime.h>
#include <hip/hip_bf16.h>

#define B_   4
#define DENC 512
#define T_   200
#define DDEC 640
#define U_   100
#define H_   640
#define V_   1025
#define VPAD 1152

typedef float f32x4 __attribute__((ext_vector_type(4)));
typedef __bf16 bf16x8 __attribute__((ext_vector_type(8)));
typedef unsigned short u16x8 __attribute__((ext_vector_type(8)));

__device__ __forceinline__ float bf2f(unsigned short s) {
    return __uint_as_float(((unsigned)s) << 16);
}

__device__ __forceinline__ unsigned addrelu_pk(unsigned e, unsigned d) {
    float elo = __uint_as_float(e << 16);
    float ehi = __uint_as_float(e & 0xffff0000u);
    float dlo = __uint_as_float(d << 16);
    float dhi = __uint_as_float(d & 0xffff0000u);
    float lo = fmaxf(elo + dlo, 0.f);
    float hi = fmaxf(ehi + dhi, 0.f);
    unsigned r;
    asm("v_cvt_pk_bf16_f32 %0, %1, %2" : "=v"(r) : "v"(lo), "v"(hi));
    return r;
}

__device__ __forceinline__ void gload_lds16(const void* g, void* l) {
    __builtin_amdgcn_global_load_lds(
        (const __attribute__((address_space(1))) unsigned int*)g,
        (__attribute__((address_space(3))) unsigned int*)l, 16, 0, 0);
}

// ---------------- K1: enc_proj (round-8 proven version)
__global__ __launch_bounds__(128) void enc_proj_kernel(
    const float* __restrict__ enc, const float* __restrict__ W,
    const float* __restrict__ bias, __hip_bfloat16* __restrict__ out)
{
    int hc = blockIdx.x, tg = blockIdx.y, b = blockIdx.z;
    int h  = hc * 128 + threadIdx.x;
    int t0 = tg * 8;
    const float* ec = enc + (size_t)b * DENC * T_ + t0;
    const float* Wc = W + h;
    float acc[8] = {0.f,0.f,0.f,0.f,0.f,0.f,0.f,0.f};
    #pragma unroll 8
    for (int d = 0; d < DENC; ++d) {
        float w = Wc[(size_t)d * H_];
        float4 e0 = *(const float4*)(ec + (size_t)d * T_);
        float4 e1 = *(const float4*)(ec + (size_t)d * T_ + 4);
        acc[0] += w * e0.x; acc[1] += w * e0.y; acc[2] += w * e0.z; acc[3] += w * e0.w;
        acc[4] += w * e1.x; acc[5] += w * e1.y; acc[6] += w * e1.z; acc[7] += w * e1.w;
    }
    float bb = bias[h];
    #pragma unroll
    for (int i = 0; i < 8; ++i)
        out[((size_t)b * T_ + t0 + i) * H_ + h] = __float2bfloat16(acc[i] + bb);
}

// ---------------- K2: dec_proj (round-8 proven version)
__global__ __launch_bounds__(128) void dec_proj_kernel(
    const float* __restrict__ dec, const float* __restrict__ W,
    const float* __restrict__ bias, __hip_bfloat16* __restrict__ out)
{
    int hc = blockIdx.x, ug = blockIdx.y, b = blockIdx.z;
    int h  = hc * 128 + threadIdx.x;
    int u0 = ug * 4;
    const float* dc = dec + (size_t)b * DDEC * U_ + u0;
    const float* Wc = W + h;
    float acc[4] = {0.f,0.f,0.f,0.f};
    #pragma unroll 8
    for (int d = 0; d < DDEC; ++d) {
        float w = Wc[(size_t)d * H_];
        float4 e0 = *(const float4*)(dc + (size_t)d * U_);
        acc[0] += w * e0.x; acc[1] += w * e0.y; acc[2] += w * e0.z; acc[3] += w * e0.w;
    }
    float bb = bias[h];
    #pragma unroll
    for (int i = 0; i < 4; ++i)
        out[((size_t)b * U_ + u0 + i) * H_ + h] = __float2bfloat16(acc[i] + bb);
}

// ---------------- K3: Wt transpose (unchanged)
__global__ __launch_bounds__(256) void wt_transpose_kernel(
    const float* __restrict__ W, unsigned short* __restrict__ Wt)
{
    int hc = blockIdx.x, vc = blockIdx.y;
    int h0 = hc * 64, v0 = vc * 64;
    __shared__ float tile[64][65];
    int tid = threadIdx.x;
    #pragma unroll
    for (int it = 0; it < 16; ++it) {
        int hl = it * 4 + (tid >> 6);
        int vl = tid & 63;
        int v = v0 + vl;
        tile[hl][vl] = (v < V_) ? W[(size_t)(h0 + hl) * V_ + v] : 0.f;
    }
    __syncthreads();
    #pragma unroll
    for (int it = 0; it < 16; ++it) {
        int vl = it * 4 + (tid >> 6);
        int hl = tid & 63;
        __bf16 bv = (__bf16)tile[hl][vl];
        Wt[(size_t)(v0 + vl) * H_ + h0 + hl] = *(unsigned short*)&bv;
    }
}

// ---------------- K4: barrier-free joint GEMM
// 512 thr = 8 waves. Block = 64 rows (8t x 8u) x 1024 v-cols (vi loop of 2 x 512).
// A (relu(enc+dec), bf16) staged ONCE full-K in 80KB DYNAMIC LDS (ds_write, swizzled),
// one __syncthreads total. B wave-private: wave w owns 64 cols, staged per-K-step via
// global_load_lds into STATIC LDS dbuf (r8 swizzle), guarded by per-wave vmcnt(4).
__global__ __launch_bounds__(512) void joint_kernel(
    const unsigned short* __restrict__ encP,   // [B,T,H] bf16
    const unsigned short* __restrict__ decP,   // [B,U,H] bf16
    const unsigned short* __restrict__ Wt,     // [VPAD][H] bf16
    const float* __restrict__ b_out,           // [V]
    float* __restrict__ out)                   // [B,T,U,V] f32
{
    extern __shared__ uint4 LA[];              // [64 rows][80 chunks] = 80 KB dynamic
    __shared__ uint4 LB[8][2][64][4];          // 8 waves x dbuf x 64 cols x 4 chunks = 64 KB

    int tu = blockIdx.x;                       // 0..324 (25 t-tiles x 13 u-tiles)
    int b  = blockIdx.y;
    int tt = tu / 13, ut = tu % 13;
    int t0 = tt * 8, u0 = ut * 8;
    int tid = threadIdx.x, lane = tid & 63, w = tid >> 6;
    int lrow = lane & 15, kg = lane >> 4;

    // ---- B gload source pointers (r8's proven pre-swizzled-source pattern)
    int pcB = lane & 3;
    const unsigned short* gB[4];
    #pragma unroll
    for (int m = 0; m < 4; ++m) {
        int cl = w * 64 + m * 16 + (lane >> 2);        // local col 0..511
        gB[m] = Wt + (size_t)cl * H_ + (size_t)((pcB ^ ((cl >> 1) & 3)) * 8);
    }

    // ---- prologue: issue B(vi=0,kt=0) into buf 0 (4 gloads, stay in flight over A-build)
    #pragma unroll
    for (int m = 0; m < 4; ++m)
        gload_lds16(gB[m], &LB[w][0][m * 16][0]);

    // ---- build A once: 64 rows x 80 chunks bf16, swizzle phys = c ^ (r&7)
    #pragma unroll
    for (int it = 0; it < 10; ++it) {
        int f = tid + it * 512;
        int r = f / 80, c = f % 80;
        int ta = t0 + (r >> 3);                         // < 200 always
        int ua = u0 + (r & 7); if (ua > U_ - 1) ua = U_ - 1;
        uint4 E = *(const uint4*)(encP + ((size_t)b * T_ + ta) * H_ + c * 8);
        uint4 D = *(const uint4*)(decP + ((size_t)b * U_ + ua) * H_ + c * 8);
        uint4 x;
        x.x = addrelu_pk(E.x, D.x); x.y = addrelu_pk(E.y, D.y);
        x.z = addrelu_pk(E.z, D.z); x.w = addrelu_pk(E.w, D.w);
        LA[r * 80 + (c ^ (r & 7))] = x;
    }
    __syncthreads();                                    // the ONLY barrier

    // ---- main loop: vi (2 col-halves) x kt (20 K-steps), barrier-free
    #pragma unroll 1
    for (int vi = 0; vi < 2; ++vi) {
        f32x4 acc[4][4];
        #pragma unroll
        for (int i = 0; i < 4; ++i)
            #pragma unroll
            for (int j = 0; j < 4; ++j)
                acc[i][j] = (f32x4){0.f, 0.f, 0.f, 0.f};

        #pragma unroll 2
        for (int kt = 0; kt < 20; ++kt) {
            int s = vi * 20 + kt;
            // issue B(s+1) into the other buffer, then wait for B(s) only (counted)
            if (s < 39) {
                int nvi = (kt < 19) ? vi : vi + 1;
                int nkt = (kt < 19) ? kt + 1 : 0;
                size_t coff = (size_t)nvi * 512 * H_ + (size_t)nkt * 32;
                #pragma unroll
                for (int m = 0; m < 4; ++m)
                    gload_lds16(gB[m] + coff, &LB[w][(kt + 1) & 1][m * 16][0]);
                asm volatile("s_waitcnt vmcnt(4)" ::: "memory");
            } else {
                asm volatile("s_waitcnt vmcnt(0)" ::: "memory");
            }
            bf16x8 a[4], bq[4];
            #pragma unroll
            for (int i = 0; i < 4; ++i) {
                int row = i * 16 + lrow;
                a[i] = __builtin_bit_cast(bf16x8, LA[row * 80 + ((kt * 4 + kg) ^ (row & 7))]);
            }
            #pragma unroll
            for (int j = 0; j < 4; ++j) {
                int col = j * 16 + lrow;
                bq[j] = __builtin_bit_cast(bf16x8, LB[w][kt & 1][col][kg ^ ((col >> 1) & 3)]);
            }
            #pragma unroll
            for (int i = 0; i < 4; ++i)
                #pragma unroll
                for (int j = 0; j < 4; ++j)
                    acc[i][j] = __builtin_amdgcn_mfma_f32_16x16x32_bf16(a[i], bq[j], acc[i][j], 0, 0, 0);
        }

        // per-vi epilogue: D col = lane&15, row = kg*4 + q
        #pragma unroll
        for (int j = 0; j < 4; ++j) {
            int v = vi * 512 + w * 64 + j * 16 + lrow;
            float bo = b_out[v];
            #pragma unroll
            for (int i = 0; i < 4; ++i) {
                #pragma unroll
                for (int q = 0; q < 4; ++q) {
                    int row = i * 16 + kg * 4 + q;
                    int t = t0 + (row >> 3);
                    int u = u0 + (row & 7);
                    if (u < U_)
                        out[(((size_t)b * T_ + t) * U_ + u) * V_ + v] = acc[i][j][q] + bo;
                }
            }
        }
    }
}

// ---------------- K5: last output column v=1024 (round-8 version)
__global__ __launch_bounds__(256) void lastcol_kernel(
    const unsigned short* __restrict__ encP, const unsigned short* __restrict__ decP,
    const unsigned short* __restrict__ Wt, const float* __restrict__ b_out,
    float* __restrict__ out)
{
    int idx = blockIdx.x * 256 + threadIdx.x;
    if (idx >= B_ * T_ * U_) return;
    int u = idx % U_;
    int t = (idx / U_) % T_;
    int b = idx / (U_ * T_);
    const u16x8* e = (const u16x8*)(encP + ((size_t)b * T_ + t) * H_);
    const u16x8* d = (const u16x8*)(decP + ((size_t)b * U_ + u) * H_);
    const u16x8* wv = (const u16x8*)(Wt + (size_t)1024 * H_);
    float acc = 0.f;
    for (int c = 0; c < H_ / 8; ++c) {
        u16x8 ev = e[c], dv = d[c], wq = wv[c];
        #pragma unroll
        for (int m = 0; m < 8; ++m)
            acc += fmaxf(bf2f(ev[m]) + bf2f(dv[m]), 0.f) * bf2f(wq[m]);
    }
    out[((size_t)(b * T_ + t) * U_ + u) * V_ + 1024] = acc + b_out[1024];
}

extern "C" void kernel_launch(void* const* d_in, const int* in_sizes, int n_in,
                              void* d_out, int out_size, void* d_ws, size_t ws_size,
                              hipStream_t stream) {
    const float* enc    = (const float*)d_in[0];
    const float* dec    = (const float*)d_in[1];
    const float* W_enc  = (const float*)d_in[2];
    const float* b_enc  = (const float*)d_in[3];
    const float* W_pred = (const float*)d_in[4];
    const float* b_pred = (const float*)d_in[5];
    const float* W_out  = (const float*)d_in[6];
    const float* b_out  = (const float*)d_in[7];
    float* out = (float*)d_out;

    char* ws = (char*)d_ws;
    __hip_bfloat16* encP = (__hip_bfloat16*)ws;                       // 1,024,000 B
    __hip_bfloat16* decP = (__hip_bfloat16*)(ws + 1024000);           //   512,000 B
    unsigned short* Wt   = (unsigned short*)(ws + 1024000 + 512000);  // 1,474,560 B

    (void)hipFuncSetAttribute((const void*)joint_kernel,
                              hipFuncAttributeMaxDynamicSharedMemorySize, 81920);

    enc_proj_kernel<<<dim3(5, 25, 4), 128, 0, stream>>>(enc, W_enc, b_enc, encP);
    dec_proj_kernel<<<dim3(5, 25, 4), 128, 0, stream>>>(dec, W_pred, b_pred, decP);
    wt_transpose_kernel<<<dim3(10, 18), 256, 0, stream>>>(W_out, Wt);
    joint_kernel<<<dim3(325, 4), 512, 81920, stream>>>(
        (const unsigned short*)encP, (const unsigned short*)decP, Wt, b_out, out);
    lastcol_kernel<<<dim3((B_ * T_ * U_ + 255) / 256), 256, 0, stream>>>(
        (const unsigned short*)encP, (const unsigned short*)decP, Wt, b_out, out);
}

// Round 13
// 414.835 us; speedup vs baseline: 1.1547x; 1.0812x over previous
//
#include <hip/hip_runtime.h>
#include <hip/hip_bf16.h>

#define B_   4
#define DENC 512
#define T_   200
#define DDEC 640
#define U_   100
#define H_   640
#define V_   1025
#define VPAD 1152

typedef float f32x4 __attribute__((ext_vector_type(4)));
typedef __bf16 bf16x8 __attribute__((ext_vector_type(8)));
typedef unsigned short u16x8 __attribute__((ext_vector_type(8)));

__device__ __forceinline__ float bf2f(unsigned short s) {
    return __uint_as_float(((unsigned)s) << 16);
}

__device__ __forceinline__ unsigned addrelu_pk(unsigned e, unsigned d) {
    float elo = __uint_as_float(e << 16);
    float ehi = __uint_as_float(e & 0xffff0000u);
    float dlo = __uint_as_float(d << 16);
    float dhi = __uint_as_float(d & 0xffff0000u);
    float lo = fmaxf(elo + dlo, 0.f);
    float hi = fmaxf(ehi + dhi, 0.f);
    unsigned r;
    asm("v_cvt_pk_bf16_f32 %0, %1, %2" : "=v"(r) : "v"(lo), "v"(hi));
    return r;
}

__device__ __forceinline__ void gload_lds16(const void* g, void* l) {
    __builtin_amdgcn_global_load_lds(
        (const __attribute__((address_space(1))) unsigned int*)g,
        (__attribute__((address_space(3))) unsigned int*)l, 16, 0, 0);
}

// ---------------- K1: fused prep: enc_proj | dec_proj | wt_transpose (one launch)
// blocks [0,260): enc   [260,520): dec   [520,700): wt
__global__ __launch_bounds__(256) void prep_fused_kernel(
    const float* __restrict__ enc, const float* __restrict__ W_enc,
    const float* __restrict__ b_enc,
    const float* __restrict__ dec, const float* __restrict__ W_pred,
    const float* __restrict__ b_pred,
    const float* __restrict__ W_out,
    __hip_bfloat16* __restrict__ encP, __hip_bfloat16* __restrict__ decP,
    unsigned short* __restrict__ Wt)
{
    __shared__ float tile[64][65];
    int bx = blockIdx.x;
    int tid = threadIdx.x;

    if (bx < 260) {
        // ---- enc_proj: b = bx/65; hc = (bx%65)/13; tg = (bx%65)%13
        int b = bx / 65, r5 = bx % 65, hc = r5 / 13, tg = r5 % 13;
        int h  = hc * 128 + (tid & 127);
        int t0 = tg * 16 + (tid >> 7) * 8;
        if (t0 >= T_) return;
        const float* ec = enc + (size_t)b * DENC * T_ + t0;
        const float* Wc = W_enc + h;
        float acc[8] = {0.f,0.f,0.f,0.f,0.f,0.f,0.f,0.f};
        #pragma unroll 8
        for (int d = 0; d < DENC; ++d) {
            float w = Wc[(size_t)d * H_];
            float4 e0 = *(const float4*)(ec + (size_t)d * T_);
            float4 e1 = *(const float4*)(ec + (size_t)d * T_ + 4);
            acc[0] += w * e0.x; acc[1] += w * e0.y; acc[2] += w * e0.z; acc[3] += w * e0.w;
            acc[4] += w * e1.x; acc[5] += w * e1.y; acc[6] += w * e1.z; acc[7] += w * e1.w;
        }
        float bb = b_enc[h];
        #pragma unroll
        for (int i = 0; i < 8; ++i)
            encP[((size_t)b * T_ + t0 + i) * H_ + h] = __float2bfloat16(acc[i] + bb);
    } else if (bx < 520) {
        // ---- dec_proj
        int i5 = bx - 260;
        int b = i5 / 65, r5 = i5 % 65, hc = r5 / 13, ug = r5 % 13;
        int h  = hc * 128 + (tid & 127);
        int u0 = ug * 8 + (tid >> 7) * 4;
        if (u0 >= U_) return;
        const float* dc = dec + (size_t)b * DDEC * U_ + u0;
        const float* Wc = W_pred + h;
        float acc[4] = {0.f,0.f,0.f,0.f};
        #pragma unroll 8
        for (int d = 0; d < DDEC; ++d) {
            float w = Wc[(size_t)d * H_];
            float4 e0 = *(const float4*)(dc + (size_t)d * U_);
            acc[0] += w * e0.x; acc[1] += w * e0.y; acc[2] += w * e0.z; acc[3] += w * e0.w;
        }
        float bb = b_pred[h];
        #pragma unroll
        for (int i = 0; i < 4; ++i)
            decP[((size_t)b * U_ + u0 + i) * H_ + h] = __float2bfloat16(acc[i] + bb);
    } else {
        // ---- wt_transpose: Wt[v][h] = bf16(W_out[h][v]), v padded to VPAD with 0
        int j = bx - 520;
        int hc = j / 18, vc = j % 18;
        int h0 = hc * 64, v0 = vc * 64;
        #pragma unroll
        for (int it = 0; it < 16; ++it) {
            int hl = it * 4 + (tid >> 6);
            int vl = tid & 63;
            int v = v0 + vl;
            tile[hl][vl] = (v < V_) ? W_out[(size_t)(h0 + hl) * V_ + v] : 0.f;
        }
        __syncthreads();
        #pragma unroll
        for (int it = 0; it < 16; ++it) {
            int vl = it * 4 + (tid >> 6);
            int hl = tid & 63;
            __bf16 bv = (__bf16)tile[hl][vl];
            Wt[(size_t)(v0 + vl) * H_ + h0 + hl] = *(unsigned short*)&bv;
        }
    }
}

// ---------------- K4: r8 2-phase skeleton, widened: 8 waves, 64 rows x 512 v-cols
// Per wave: 64 rows x 64 cols = acc[4][4], 16 MFMA/step; BK=32, 20 K-steps.
// A-build redundancy 2x (vs r8's 4x); per-thread gloads/step unchanged (4).
// LDS all-dynamic 72KB: LB [2][512][4] uint4 at 0, LA [2][64][4] uint4 at +64KB.
// Swizzles byte-identical to r8: chunk phys = kc ^ ((row>>1)&3), gload src pre-swizzled.
__global__ __launch_bounds__(512, 4) void joint_kernel(
    const unsigned short* __restrict__ encP,   // [B,T,H] bf16
    const unsigned short* __restrict__ decP,   // [B,U,H] bf16
    const unsigned short* __restrict__ Wt,     // [VPAD][H] bf16
    const float* __restrict__ b_out,           // [V]
    float* __restrict__ out)                   // [B,T,U,V] f32
{
    extern __shared__ uint4 LDS[];
    uint4* LB = LDS;                           // [2][512][4] = 4096 uint4 = 64 KB
    uint4* LA = LDS + 4096;                    // [2][64][4]  =  512 uint4 =  8 KB

    int vi = blockIdx.x;                       // 0..1
    int tu = blockIdx.y;                       // 0..324
    int b  = blockIdx.z;
    int tt = tu / 13, ut = tu % 13;
    int t0 = tt * 8, u0 = ut * 8, vb = vi * 512;
    int tid = threadIdx.x;
    int lane = tid & 63, w = tid >> 6;         // wave 0..7 = col-group
    int lrow = lane & 15, kg = lane >> 4;

    // ---- A-build mapping (threads 0..255): row r (0..63), chunk kc (0..3)
    int r  = tid >> 2, kc = tid & 3;
    int ta = t0 + (r >> 3);                    // < 200 always
    int ua = u0 + (r & 7); if (ua > U_ - 1) ua = U_ - 1;
    const unsigned short* eR = encP + ((size_t)b * T_ + ta) * H_ + kc * 8;
    const unsigned short* dR = decP + ((size_t)b * U_ + ua) * H_ + kc * 8;
    int fA = (r >> 1) & 3;
    bool buildA = (tid < 256);

    // ---- B gload mapping: wave w stages local cols 64w..64w+63; 4 instrs of 16 cols
    int pcB = lane & 3;
    const unsigned short* gB[4];
    #pragma unroll
    for (int m = 0; m < 4; ++m) {
        int cl = w * 64 + m * 16 + (lane >> 2);
        gB[m] = Wt + (size_t)(vb + cl) * H_ + (size_t)((pcB ^ ((cl >> 1) & 3)) * 8);
    }

    f32x4 acc[4][4];
    #pragma unroll
    for (int i = 0; i < 4; ++i)
        #pragma unroll
        for (int j = 0; j < 4; ++j)
            acc[i][j] = (f32x4){0.f, 0.f, 0.f, 0.f};

    // ---- prologue: stage k-step 0 into buf 0
    {
        if (buildA) {
            uint4 E = *(const uint4*)(eR);
            uint4 D = *(const uint4*)(dR);
            uint4 x;
            x.x = addrelu_pk(E.x, D.x); x.y = addrelu_pk(E.y, D.y);
            x.z = addrelu_pk(E.z, D.z); x.w = addrelu_pk(E.w, D.w);
            LA[(0 * 64 + r) * 4 + (kc ^ fA)] = x;
        }
        #pragma unroll
        for (int m = 0; m < 4; ++m)
            gload_lds16(gB[m], &LB[(size_t)(0 * 512 + w * 64 + m * 16) * 4]);
    }
    __syncthreads();

    // ---- main K loop: 20 steps of K=32
    #pragma unroll 2
    for (int kt = 0; kt < 20; ++kt) {
        int cur = kt & 1;
        uint4 En, Dn;
        if (kt < 19) {
            if (buildA) {
                En = *(const uint4*)(eR + (kt + 1) * 32);
                Dn = *(const uint4*)(dR + (kt + 1) * 32);
            }
            #pragma unroll
            for (int m = 0; m < 4; ++m)
                gload_lds16(gB[m] + (kt + 1) * 32,
                            &LB[(size_t)((cur ^ 1) * 512 + w * 64 + m * 16) * 4]);
        }
        bf16x8 a[4], bq[4];
        #pragma unroll
        for (int i = 0; i < 4; ++i) {
            int row = i * 16 + lrow;
            a[i] = __builtin_bit_cast(bf16x8, LA[(cur * 64 + row) * 4 + (kg ^ ((row >> 1) & 3))]);
        }
        #pragma unroll
        for (int j = 0; j < 4; ++j) {
            int col = w * 64 + j * 16 + lrow;
            bq[j] = __builtin_bit_cast(bf16x8, LB[(cur * 512 + col) * 4 + (kg ^ ((col >> 1) & 3))]);
        }
        #pragma unroll
        for (int i = 0; i < 4; ++i)
            #pragma unroll
            for (int j = 0; j < 4; ++j)
                acc[i][j] = __builtin_amdgcn_mfma_f32_16x16x32_bf16(a[i], bq[j], acc[i][j], 0, 0, 0);
        if (kt < 19 && buildA) {
            uint4 x;
            x.x = addrelu_pk(En.x, Dn.x); x.y = addrelu_pk(En.y, Dn.y);
            x.z = addrelu_pk(En.z, Dn.z); x.w = addrelu_pk(En.w, Dn.w);
            LA[((cur ^ 1) * 64 + r) * 4 + (kc ^ fA)] = x;
        }
        __syncthreads();
    }

    // ---- epilogue: D col = lane&15, row = kg*4 + q   (v = vb+... < 1024 always)
    #pragma unroll
    for (int j = 0; j < 4; ++j) {
        int v = vb + w * 64 + j * 16 + lrow;
        float bo = b_out[v];
        #pragma unroll
        for (int i = 0; i < 4; ++i) {
            #pragma unroll
            for (int q = 0; q < 4; ++q) {
                int row = i * 16 + kg * 4 + q;
                int t = t0 + (row >> 3);
                int u = u0 + (row & 7);
                if (u < U_)
                    out[(((size_t)b * T_ + t) * U_ + u) * V_ + v] = acc[i][j][q] + bo;
            }
        }
    }
}

// ---------------- K5: last output column v=1024 (unchanged)
__global__ __launch_bounds__(256) void lastcol_kernel(
    const unsigned short* __restrict__ encP, const unsigned short* __restrict__ decP,
    const unsigned short* __restrict__ Wt, const float* __restrict__ b_out,
    float* __restrict__ out)
{
    int idx = blockIdx.x * 256 + threadIdx.x;
    if (idx >= B_ * T_ * U_) return;
    int u = idx % U_;
    int t = (idx / U_) % T_;
    int b = idx / (U_ * T_);
    const u16x8* e = (const u16x8*)(encP + ((size_t)b * T_ + t) * H_);
    const u16x8* d = (const u16x8*)(decP + ((size_t)b * U_ + u) * H_);
    const u16x8* wv = (const u16x8*)(Wt + (size_t)1024 * H_);
    float acc = 0.f;
    for (int c = 0; c < H_ / 8; ++c) {
        u16x8 ev = e[c], dv = d[c], wq = wv[c];
        #pragma unroll
        for (int m = 0; m < 8; ++m)
            acc += fmaxf(bf2f(ev[m]) + bf2f(dv[m]), 0.f) * bf2f(wq[m]);
    }
    out[((size_t)(b * T_ + t) * U_ + u) * V_ + 1024] = acc + b_out[1024];
}

extern "C" void kernel_launch(void* const* d_in, const int* in_sizes, int n_in,
                              void* d_out, int out_size, void* d_ws, size_t ws_size,
                              hipStream_t stream) {
    const float* enc    = (const float*)d_in[0];
    const float* dec    = (const float*)d_in[1];
    const float* W_enc  = (const float*)d_in[2];
    const float* b_enc  = (const float*)d_in[3];
    const float* W_pred = (const float*)d_in[4];
    const float* b_pred = (const float*)d_in[5];
    const float* W_out  = (const float*)d_in[6];
    const float* b_out  = (const float*)d_in[7];
    float* out = (float*)d_out;

    char* ws = (char*)d_ws;
    __hip_bfloat16* encP = (__hip_bfloat16*)ws;                       // 1,024,000 B
    __hip_bfloat16* decP = (__hip_bfloat16*)(ws + 1024000);           //   512,000 B
    unsigned short* Wt   = (unsigned short*)(ws + 1024000 + 512000);  // 1,474,560 B

    (void)hipFuncSetAttribute((const void*)joint_kernel,
                              hipFuncAttributeMaxDynamicSharedMemorySize, 73728);

    prep_fused_kernel<<<dim3(700), 256, 0, stream>>>(
        enc, W_enc, b_enc, dec, W_pred, b_pred, W_out, encP, decP, Wt);
    joint_kernel<<<dim3(2, 325, 4), 512, 73728, stream>>>(
        (const unsigned short*)encP, (const unsigned short*)decP, Wt, b_out, out);
    lastcol_kernel<<<dim3((B_ * T_ * U_ + 255) / 256), 256, 0, stream>>>(
        (const unsigned short*)encP, (const unsigned short*)decP, Wt, b_out, out);
}

// Round 14
// 365.509 us; speedup vs baseline: 1.3105x; 1.1349x over previous
//
#include <hip/hip_runtime.h>
#include <hip/hip_bf16.h>

#define B_   4
#define DENC 512
#define T_   200
#define DDEC 640
#define U_   100
#define H_   640
#define V_   1025
#define VPAD 1152

typedef float f32x4 __attribute__((ext_vector_type(4)));
typedef __bf16 bf16x8 __attribute__((ext_vector_type(8)));
typedef unsigned short u16x8 __attribute__((ext_vector_type(8)));

__device__ __forceinline__ float bf2f(unsigned short s) {
    return __uint_as_float(((unsigned)s) << 16);
}

__device__ __forceinline__ unsigned addrelu_pk(unsigned e, unsigned d) {
    float elo = __uint_as_float(e << 16);
    float ehi = __uint_as_float(e & 0xffff0000u);
    float dlo = __uint_as_float(d << 16);
    float dhi = __uint_as_float(d & 0xffff0000u);
    float lo = fmaxf(elo + dlo, 0.f);
    float hi = fmaxf(ehi + dhi, 0.f);
    unsigned r;
    asm("v_cvt_pk_bf16_f32 %0, %1, %2" : "=v"(r) : "v"(lo), "v"(hi));
    return r;
}

__device__ __forceinline__ void gload_lds16(const void* g, void* l) {
    __builtin_amdgcn_global_load_lds(
        (const __attribute__((address_space(1))) unsigned int*)g,
        (__attribute__((address_space(3))) unsigned int*)l, 16, 0, 0);
}

// ---------------- K1: fused prep (r13-proven): enc_proj | dec_proj | wt_transpose
// blocks [0,260): enc   [260,520): dec   [520,700): wt
__global__ __launch_bounds__(256) void prep_fused_kernel(
    const float* __restrict__ enc, const float* __restrict__ W_enc,
    const float* __restrict__ b_enc,
    const float* __restrict__ dec, const float* __restrict__ W_pred,
    const float* __restrict__ b_pred,
    const float* __restrict__ W_out,
    __hip_bfloat16* __restrict__ encP, __hip_bfloat16* __restrict__ decP,
    unsigned short* __restrict__ Wt)
{
    __shared__ float tile[64][65];
    int bx = blockIdx.x;
    int tid = threadIdx.x;

    if (bx < 260) {
        int b = bx / 65, r5 = bx % 65, hc = r5 / 13, tg = r5 % 13;
        int h  = hc * 128 + (tid & 127);
        int t0 = tg * 16 + (tid >> 7) * 8;
        if (t0 >= T_) return;
        const float* ec = enc + (size_t)b * DENC * T_ + t0;
        const float* Wc = W_enc + h;
        float acc[8] = {0.f,0.f,0.f,0.f,0.f,0.f,0.f,0.f};
        #pragma unroll 8
        for (int d = 0; d < DENC; ++d) {
            float w = Wc[(size_t)d * H_];
            float4 e0 = *(const float4*)(ec + (size_t)d * T_);
            float4 e1 = *(const float4*)(ec + (size_t)d * T_ + 4);
            acc[0] += w * e0.x; acc[1] += w * e0.y; acc[2] += w * e0.z; acc[3] += w * e0.w;
            acc[4] += w * e1.x; acc[5] += w * e1.y; acc[6] += w * e1.z; acc[7] += w * e1.w;
        }
        float bb = b_enc[h];
        #pragma unroll
        for (int i = 0; i < 8; ++i)
            encP[((size_t)b * T_ + t0 + i) * H_ + h] = __float2bfloat16(acc[i] + bb);
    } else if (bx < 520) {
        int i5 = bx - 260;
        int b = i5 / 65, r5 = i5 % 65, hc = r5 / 13, ug = r5 % 13;
        int h  = hc * 128 + (tid & 127);
        int u0 = ug * 8 + (tid >> 7) * 4;
        if (u0 >= U_) return;
        const float* dc = dec + (size_t)b * DDEC * U_ + u0;
        const float* Wc = W_pred + h;
        float acc[4] = {0.f,0.f,0.f,0.f};
        #pragma unroll 8
        for (int d = 0; d < DDEC; ++d) {
            float w = Wc[(size_t)d * H_];
            float4 e0 = *(const float4*)(dc + (size_t)d * U_);
            acc[0] += w * e0.x; acc[1] += w * e0.y; acc[2] += w * e0.z; acc[3] += w * e0.w;
        }
        float bb = b_pred[h];
        #pragma unroll
        for (int i = 0; i < 4; ++i)
            decP[((size_t)b * U_ + u0 + i) * H_ + h] = __float2bfloat16(acc[i] + bb);
    } else {
        int j = bx - 520;
        int hc = j / 18, vc = j % 18;
        int h0 = hc * 64, v0 = vc * 64;
        #pragma unroll
        for (int it = 0; it < 16; ++it) {
            int hl = it * 4 + (tid >> 6);
            int vl = tid & 63;
            int v = v0 + vl;
            tile[hl][vl] = (v < V_) ? W_out[(size_t)(h0 + hl) * V_ + v] : 0.f;
        }
        __syncthreads();
        #pragma unroll
        for (int it = 0; it < 16; ++it) {
            int vl = it * 4 + (tid >> 6);
            int hl = tid & 63;
            __bf16 bv = (__bf16)tile[hl][vl];
            Wt[(size_t)(v0 + vl) * H_ + h0 + hl] = *(unsigned short*)&bv;
        }
    }
}

// ---------------- K4: r8 joint kernel (proven 287us) + XCD-aware block swizzle (T1)
// Flat grid 5200; decode with xcd chunking: same-vi, contiguous-tu blocks share an XCD's
// L2 (Wt slice 368KB + encP/decP 1.5MB resident per XCD). Structure byte-identical to r8.
__global__ __launch_bounds__(256) void joint_kernel(
    const unsigned short* __restrict__ encP,   // [B,T,H] bf16
    const unsigned short* __restrict__ decP,   // [B,U,H] bf16
    const unsigned short* __restrict__ Wt,     // [VPAD][H] bf16
    const float* __restrict__ b_out,           // [V]
    float* __restrict__ out)                   // [B,T,U,V] f32
{
    __shared__ uint4 LA[2][64][4];             // 8 KB
    __shared__ uint4 LB[2][256][4];            // 32 KB

    // ---- XCD swizzle: f -> n = (f&7)*650 + (f>>3); n = vi*1300 + b*325 + tu
    int f   = blockIdx.x;                      // 0..5199
    int n   = (f & 7) * 650 + (f >> 3);
    int vi  = n / 1300;
    int rem = n - vi * 1300;
    int b   = rem / 325;
    int tu  = rem - b * 325;

    int tt = tu / 13, ut = tu % 13;
    int t0 = tt * 8, u0 = ut * 8, vb = vi * 256;
    int tid = threadIdx.x;
    int lane = tid & 63, w = tid >> 6;         // w = wave = col-group 0..3
    int lrow = lane & 15, kg = lane >> 4;

    int r  = tid >> 2, kc = tid & 3;
    int ta = t0 + (r >> 3);
    int ua = u0 + (r & 7); if (ua > U_ - 1) ua = U_ - 1;
    const unsigned short* eR = encP + ((size_t)b * T_ + ta) * H_ + kc * 8;
    const unsigned short* dR = decP + ((size_t)b * U_ + ua) * H_ + kc * 8;
    int fA = (r >> 1) & 3;

    int pcB = lane & 3;
    const unsigned short* gB[4];
    #pragma unroll
    for (int m = 0; m < 4; ++m) {
        int cl = w * 64 + m * 16 + (lane >> 2);
        gB[m] = Wt + (size_t)(vb + cl) * H_ + (pcB ^ ((cl >> 1) & 3)) * 8;
    }

    f32x4 acc[4][4];
    #pragma unroll
    for (int i = 0; i < 4; ++i)
        #pragma unroll
        for (int j = 0; j < 4; ++j)
            acc[i][j] = (f32x4){0.f, 0.f, 0.f, 0.f};

    {
        uint4 E = *(const uint4*)(eR);
        uint4 D = *(const uint4*)(dR);
        uint4 x;
        x.x = addrelu_pk(E.x, D.x); x.y = addrelu_pk(E.y, D.y);
        x.z = addrelu_pk(E.z, D.z); x.w = addrelu_pk(E.w, D.w);
        LA[0][r][kc ^ fA] = x;
        #pragma unroll
        for (int m = 0; m < 4; ++m)
            gload_lds16(gB[m], &LB[0][w * 64 + m * 16][0]);
    }
    __syncthreads();

    #pragma unroll 2
    for (int kt = 0; kt < 20; ++kt) {
        int cur = kt & 1;
        uint4 En, Dn;
        if (kt < 19) {
            En = *(const uint4*)(eR + (kt + 1) * 32);
            Dn = *(const uint4*)(dR + (kt + 1) * 32);
            #pragma unroll
            for (int m = 0; m < 4; ++m)
                gload_lds16(gB[m] + (kt + 1) * 32, &LB[cur ^ 1][w * 64 + m * 16][0]);
        }
        bf16x8 a[4], bq[4];
        #pragma unroll
        for (int i = 0; i < 4; ++i) {
            int row = i * 16 + lrow;
            a[i] = __builtin_bit_cast(bf16x8, LA[cur][row][kg ^ ((row >> 1) & 3)]);
        }
        #pragma unroll
        for (int j = 0; j < 4; ++j) {
            int col = w * 64 + j * 16 + lrow;
            bq[j] = __builtin_bit_cast(bf16x8, LB[cur][col][kg ^ ((col >> 1) & 3)]);
        }
        #pragma unroll
        for (int i = 0; i < 4; ++i)
            #pragma unroll
            for (int j = 0; j < 4; ++j)
                acc[i][j] = __builtin_amdgcn_mfma_f32_16x16x32_bf16(a[i], bq[j], acc[i][j], 0, 0, 0);
        if (kt < 19) {
            uint4 x;
            x.x = addrelu_pk(En.x, Dn.x); x.y = addrelu_pk(En.y, Dn.y);
            x.z = addrelu_pk(En.z, Dn.z); x.w = addrelu_pk(En.w, Dn.w);
            LA[cur ^ 1][r][kc ^ fA] = x;
        }
        __syncthreads();
    }

    #pragma unroll
    for (int j = 0; j < 4; ++j) {
        int v = vb + w * 64 + j * 16 + lrow;
        float bo = b_out[v];
        #pragma unroll
        for (int i = 0; i < 4; ++i) {
            #pragma unroll
            for (int q = 0; q < 4; ++q) {
                int row = i * 16 + kg * 4 + q;
                int t = t0 + (row >> 3);
                int u = u0 + (row & 7);
                if (u < U_)
                    out[(((size_t)b * T_ + t) * U_ + u) * V_ + v] = acc[i][j][q] + bo;
            }
        }
    }
}

// ---------------- K5: last output column v=1024 (unchanged r8)
__global__ __launch_bounds__(256) void lastcol_kernel(
    const unsigned short* __restrict__ encP, const unsigned short* __restrict__ decP,
    const unsigned short* __restrict__ Wt, const float* __restrict__ b_out,
    float* __restrict__ out)
{
    int idx = blockIdx.x * 256 + threadIdx.x;
    if (idx >= B_ * T_ * U_) return;
    int u = idx % U_;
    int t = (idx / U_) % T_;
    int b = idx / (U_ * T_);
    const u16x8* e = (const u16x8*)(encP + ((size_t)b * T_ + t) * H_);
    const u16x8* d = (const u16x8*)(decP + ((size_t)b * U_ + u) * H_);
    const u16x8* wv = (const u16x8*)(Wt + (size_t)1024 * H_);
    float acc = 0.f;
    for (int c = 0; c < H_ / 8; ++c) {
        u16x8 ev = e[c], dv = d[c], wq = wv[c];
        #pragma unroll
        for (int m = 0; m < 8; ++m)
            acc += fmaxf(bf2f(ev[m]) + bf2f(dv[m]), 0.f) * bf2f(wq[m]);
    }
    out[((size_t)(b * T_ + t) * U_ + u) * V_ + 1024] = acc + b_out[1024];
}

extern "C" void kernel_launch(void* const* d_in, const int* in_sizes, int n_in,
                              void* d_out, int out_size, void* d_ws, size_t ws_size,
                              hipStream_t stream) {
    const float* enc    = (const float*)d_in[0];
    const float* dec    = (const float*)d_in[1];
    const float* W_enc  = (const float*)d_in[2];
    const float* b_enc  = (const float*)d_in[3];
    const float* W_pred = (const float*)d_in[4];
    const float* b_pred = (const float*)d_in[5];
    const float* W_out  = (const float*)d_in[6];
    const float* b_out  = (const float*)d_in[7];
    float* out = (float*)d_out;

    char* ws = (char*)d_ws;
    __hip_bfloat16* encP = (__hip_bfloat16*)ws;                       // 1,024,000 B
    __hip_bfloat16* decP = (__hip_bfloat16*)(ws + 1024000);           //   512,000 B
    unsigned short* Wt   = (unsigned short*)(ws + 1024000 + 512000);  // 1,474,560 B

    prep_fused_kernel<<<dim3(700), 256, 0, stream>>>(
        enc, W_enc, b_enc, dec, W_pred, b_pred, W_out, encP, decP, Wt);
    joint_kernel<<<dim3(5200), 256, 0, stream>>>(
        (const unsigned short*)encP, (const unsigned short*)decP, Wt, b_out, out);
    lastcol_kernel<<<dim3((B_ * T_ * U_ + 255) / 256), 256, 0, stream>>>(
        (const unsigned short*)encP, (const unsigned short*)decP, Wt, b_out, out);
}